// Round 1
// baseline (297.641 us; speedup 1.0000x reference)
//
#include <hip/hip_runtime.h>
#include <math.h>

// TreeBackbone fused kernel (round 1: correctness-first fp32 baseline)
//
// Reference pipeline:
//   x(B,3,32,32) --grouped 5x5 conv(g=3,15 filt/grp)--> (B,45,28,28)
//   sigmoid(.+cb) -> maxpool2x2 -> (B,45,14,14)
//   rearrange -> tree contraction: out[b,o,g,h] = sum_{f,w,i,j}
//       pooled[b, g*15+f, 2h+i, 2w+j] * TW[o,f,g,h,w,i,j]
//   sigmoid(.+tb) -> (B, 336)
//
// Design: one block (256 thr) per image; everything staged in LDS.
// sigmoid+maxpool commute (monotonic) -> pool pre-activations, 1 exp/pooled.

#define BLOCK 256

__global__ __launch_bounds__(BLOCK) void tree_backbone_fused(
    const float* __restrict__ x,    // (B,3,32,32)
    const float* __restrict__ cw,   // (45,1,5,5)
    const float* __restrict__ cb,   // (45,)
    const float* __restrict__ tw,   // (16,15,3,7,7,2,2) = (o,f,g,h,w,i,j)
    const float* __restrict__ tb,   // (16,3,7)
    float* __restrict__ out,        // (B,336)
    int B)
{
    __shared__ float s_x[3][32][32];      // 12 KB input image
    __shared__ float s_cw[45][26];        // conv weights, padded row
    __shared__ float s_cb[45];
    __shared__ float s_pool[45][196];     // 35.3 KB pooled map (c, py*14+px)

    const int b = blockIdx.x;
    if (b >= B) return;
    const int t = threadIdx.x;

    // ---- stage image (3072 floats as 768 float4, coalesced) ----
    {
        const float4* xs = (const float4*)(x + (size_t)b * 3 * 32 * 32);
        float4* xd = (float4*)(&s_x[0][0][0]);
        #pragma unroll
        for (int i = 0; i < 3; ++i) xd[t + i * BLOCK] = xs[t + i * BLOCK];
    }
    // ---- stage conv weights + bias ----
    for (int i = t; i < 45 * 25; i += BLOCK) s_cw[i / 25][i % 25] = cw[i];
    if (t < 45) s_cb[t] = cb[t];
    __syncthreads();

    // ---- conv + bias + maxpool(pre-act) + sigmoid : 45*14*14 = 8820 tasks ----
    for (int task = t; task < 45 * 196; task += BLOCK) {
        const int c  = task / 196;          // output channel 0..44
        const int r  = task - c * 196;      // py*14+px
        const int py = r / 14;
        const int px = r - py * 14;
        const int g  = c / 15;              // group == input channel

        float m = -1e30f;
        #pragma unroll
        for (int sy = 0; sy < 2; ++sy) {
            #pragma unroll
            for (int sx = 0; sx < 2; ++sx) {
                const int oy = 2 * py + sy;
                const int ox = 2 * px + sx;
                float acc = s_cb[c];
                #pragma unroll
                for (int ky = 0; ky < 5; ++ky) {
                    #pragma unroll
                    for (int kx = 0; kx < 5; ++kx) {
                        acc += s_x[g][oy + ky][ox + kx] * s_cw[c][ky * 5 + kx];
                    }
                }
                m = fmaxf(m, acc);
            }
        }
        // sigmoid after pooling (monotonicity: pool(sig(x)) == sig(pool(x)))
        s_pool[c][r] = 1.0f / (1.0f + __expf(-m));
    }
    __syncthreads();

    // ---- tree contraction: 336 outputs, 420 MACs each ----
    for (int idx = t; idx < 336; idx += BLOCK) {
        const int o = idx / 21;
        const int r = idx - o * 21;
        const int g = r / 7;
        const int h = r - g * 7;
        // TW strides: o:8820, f:588, g:196, h:28, w:4, i:2, j:1
        const float* wp = tw + o * 8820 + g * 196 + h * 28;
        float acc = 0.0f;
        #pragma unroll 1
        for (int f = 0; f < 15; ++f) {
            const float* wf = wp + f * 588;            // 28 contiguous floats
            const float* pp = &s_pool[g * 15 + f][0];
            #pragma unroll
            for (int w = 0; w < 7; ++w) {
                #pragma unroll
                for (int i = 0; i < 2; ++i) {
                    #pragma unroll
                    for (int j = 0; j < 2; ++j) {
                        acc += pp[(2 * h + i) * 14 + (2 * w + j)] * wf[w * 4 + i * 2 + j];
                    }
                }
            }
        }
        out[(size_t)b * 336 + idx] = 1.0f / (1.0f + __expf(-(acc + tb[idx])));
    }
}

extern "C" void kernel_launch(void* const* d_in, const int* in_sizes, int n_in,
                              void* d_out, int out_size, void* d_ws, size_t ws_size,
                              hipStream_t stream) {
    const float* x  = (const float*)d_in[0];
    const float* cw = (const float*)d_in[1];
    const float* cb = (const float*)d_in[2];
    const float* tw = (const float*)d_in[3];
    const float* tb = (const float*)d_in[4];
    float* out = (float*)d_out;

    const int B = in_sizes[0] / (3 * 32 * 32);   // 4096
    tree_backbone_fused<<<B, BLOCK, 0, stream>>>(x, cw, cb, tw, tb, out, B);
}

// Round 2
// 214.114 us; speedup vs baseline: 1.3901x; 1.3901x over previous
//
#include <hip/hip_runtime.h>
#include <math.h>

// TreeBackbone fused kernel — round 2: register-tiled conv, conflict-free LDS.
//
//   x(B,3,32,32) --grouped 5x5 conv(g=3,15/grp)--> (B,45,28,28)
//   sigmoid(.+cb) -> maxpool2x2 -> (B,45,14,14)   [pool pre-act: monotonic]
//   tree: out[b,o,g,h] = sig( sum_{f,w,i,j} pool[b,g*15+f,2h+i,2w+j]*TW[o,f,g,h,w,i,j] + tb )
//
// Conv: task = (half, c, py); thread streams 6 input rows via ds_read_b128
// into registers, keeps 2x14 conv accumulators, pools+sigmoids 7 outputs.
// s_x rows interleaved p(r)=16(r&1)+(r>>1), padded to 36 floats => the
// lane-stride Delta_r=2 becomes Delta_p=1 => b128 reads hit all 32 banks
// uniformly (conflict-free). s_pool rows padded to 197 to de-alias the
// tree phase's even-bank pattern.

#define BLOCK 256

__device__ __forceinline__ float sigmoidf_(float v) {
    return 1.0f / (1.0f + __expf(-v));
}

template<int H>
__device__ __forceinline__ void conv_half(
    const float (*sx)[36],    // s_x[g]: [32 phys rows][36]
    const float* wrow,        // s_cw[c]: 25 weights
    float cbias,
    int py,
    float* pooldst)           // &s_pool[c][py*14 + 7*H]
{
    float aA[14], aB[14];     // conv rows 2py (A) and 2py+1 (B), cols ox=14H+d
    #pragma unroll
    for (int d = 0; d < 14; ++d) { aA[d] = 0.f; aB[d] = 0.f; }

    #pragma unroll
    for (int dr = 0; dr < 6; ++dr) {
        // logical row r = 2py+dr -> physical p = 16*(r&1) + (r>>1)
        const float* rp = &sx[((dr & 1) << 4) + py + (dr >> 1)][12 * H];
        float f[20];                       // floats 12H .. 12H+19 of the row
        #pragma unroll
        for (int k = 0; k < 5; ++k)
            *(float4*)&f[4 * k] = *(const float4*)&rp[4 * k];
        // value at x-pos (14H + d) is f[d + 2H]
        if (dr <= 4) {                     // contributes to row A with ky=dr
            #pragma unroll
            for (int kx = 0; kx < 5; ++kx) {
                const float w = wrow[dr * 5 + kx];
                #pragma unroll
                for (int d = 0; d < 14; ++d)
                    aA[d] += f[d + kx + 2 * H] * w;
            }
        }
        if (dr >= 1) {                     // contributes to row B with ky=dr-1
            #pragma unroll
            for (int kx = 0; kx < 5; ++kx) {
                const float w = wrow[(dr - 1) * 5 + kx];
                #pragma unroll
                for (int d = 0; d < 14; ++d)
                    aB[d] += f[d + kx + 2 * H] * w;
            }
        }
    }
    #pragma unroll
    for (int p = 0; p < 7; ++p) {
        float m = fmaxf(fmaxf(aA[2 * p], aA[2 * p + 1]),
                        fmaxf(aB[2 * p], aB[2 * p + 1]));
        pooldst[p] = sigmoidf_(m + cbias);
    }
}

__global__ __launch_bounds__(BLOCK) void tree_backbone_fused(
    const float* __restrict__ x,    // (B,3,32,32)
    const float* __restrict__ cw,   // (45,1,5,5)
    const float* __restrict__ cb,   // (45,)
    const float* __restrict__ tw,   // (16,15,3,7,7,2,2)
    const float* __restrict__ tb,   // (16,3,7)
    float* __restrict__ out,        // (B,336)
    int B)
{
    __shared__ float s_x[3][32][36];    // 13824 B, interleaved rows
    __shared__ float s_cw[45][25];      // 4500 B
    __shared__ float s_cb[45];          // 180 B
    __shared__ float s_pool[45][197];   // 35460 B  (row pad 197)

    const int b = blockIdx.x;
    if (b >= B) return;
    const int t = threadIdx.x;

    // ---- stage image: 768 float4, coalesced global, scattered to interleave ----
    {
        const float4* xs = (const float4*)(x + (size_t)b * 3072);
        #pragma unroll
        for (int j = 0; j < 3; ++j) {
            const int i = t + j * BLOCK;           // 0..767
            const float4 v = xs[i];
            const int g = i >> 8, rem = i & 255, r = rem >> 3, q = rem & 7;
            const int p = ((r & 1) << 4) + (r >> 1);
            *(float4*)&s_x[g][p][q * 4] = v;
        }
    }
    for (int i = t; i < 45 * 25; i += BLOCK) s_cw[i / 25][i % 25] = cw[i];
    if (t < 45) s_cb[t] = cb[t];
    __syncthreads();

    // ---- conv + pool + sigmoid: 1260 tasks = (half h, c, py) h-major ----
    for (int task = t; task < 1260; task += BLOCK) {
        const int h  = (task >= 630) ? 1 : 0;
        const int tt = task - 630 * h;
        const int c  = tt / 14;
        const int py = tt - c * 14;
        const int g  = c / 15;
        if (h == 0)
            conv_half<0>(s_x[g], s_cw[c], s_cb[c], py, &s_pool[c][py * 14]);
        else
            conv_half<1>(s_x[g], s_cw[c], s_cb[c], py, &s_pool[c][py * 14 + 7]);
    }
    __syncthreads();

    // ---- tree contraction: 336 outputs, 420 MACs each ----
    for (int idx = t; idx < 336; idx += BLOCK) {
        const int o  = idx / 21;
        const int r2 = idx - o * 21;
        const int g  = r2 / 7;
        const int hh = r2 - g * 7;
        const float* wp = tw + o * 8820 + g * 196 + hh * 28;
        float acc = 0.0f;
        #pragma unroll 1
        for (int f = 0; f < 15; ++f) {
            const float4* wf = (const float4*)(wp + f * 588);   // 7 x float4
            const float* p0 = &s_pool[g * 15 + f][(2 * hh) * 14];
            const float* p1 = p0 + 14;
            #pragma unroll
            for (int w = 0; w < 7; ++w) {
                const float4 q = wf[w];
                acc += p0[2 * w]     * q.x + p0[2 * w + 1] * q.y
                     + p1[2 * w]     * q.z + p1[2 * w + 1] * q.w;
            }
        }
        out[(size_t)b * 336 + idx] = sigmoidf_(acc + tb[idx]);
    }
}

extern "C" void kernel_launch(void* const* d_in, const int* in_sizes, int n_in,
                              void* d_out, int out_size, void* d_ws, size_t ws_size,
                              hipStream_t stream) {
    const float* x  = (const float*)d_in[0];
    const float* cw = (const float*)d_in[1];
    const float* cb = (const float*)d_in[2];
    const float* tw = (const float*)d_in[3];
    const float* tb = (const float*)d_in[4];
    float* out = (float*)d_out;

    const int B = in_sizes[0] / (3 * 32 * 32);   // 4096
    tree_backbone_fused<<<B, BLOCK, 0, stream>>>(x, cw, cb, tw, tb, out, B);
}